// Round 2
// baseline (299.146 us; speedup 1.0000x reference)
//
#include <hip/hip_runtime.h>

#define NXD 512
#define NYD 512
#define CD  64
#define NPIX (NXD * NYD)
// Problem constants fixed by the reference: B=4, C=64, NX=NY=512.
//
// Window decomposition (R5, measured via rocprof): harness poisons the 1 GiB
// workspace (166-172 us @ 6.3 TB/s) + 268 MB output (~42 us) INSIDE the timed
// window => ~210 us fixed. Our kernels ~79 us vs ~46 us floor. Optimize only
// the kernel-side share; compare kernel dispatch times, not headline dur_us.
//
// R5 post-mortem: 2-quad-per-thread MLP was NEUTRAL (289->293, noise) =>
// gather is traffic-bound, not latency-bound. Remaining excess traffic is
// read amplification: the 16 channels sharing one 64B feat line lived in 16
// DIFFERENT blocks (c in bits 16-21 of the linear map) => each feat line
// fetched ~16x from L2/L3 (~327 MB scattered reads, as big as the store
// stream). R6: 1024-thread blocks = 16 waves = 16 consecutive channels over
// the SAME 64-quad span on ONE CU => winner (1 KB) and feat lines (~1.2 KB)
// are L1-broadcast across waves; read traffic drops ~16x.
//
// Round-3 lesson (measured): per-instruction 16B/lane contiguous stores +
// linear block-order streams are mandatory (R3's per-lane channel sweep
// regressed 79->155 us). R6 keeps both: each wave stores 64 contiguous
// float4s for one channel; blockIdx.x advances the pixel span linearly.
//
// Round-4 lesson: __builtin_nontemporal_store needs a NATIVE vector type,
// not HIP's float4 class. Use ext_vector_type(4).

typedef float nfloat4 __attribute__((ext_vector_type(4)));

// Init winner array to -1 (int4 stores). 4 MiB.
__global__ void ppscatter_init_winner(int4* __restrict__ win4, int n_win4) {
    int i = blockIdx.x * blockDim.x + threadIdx.x;
    if (i < n_win4) win4[i] = make_int4(-1, -1, -1, -1);
}

// Last-write-wins vote: max voxel index per flat slot wins (matches numpy
// fancy-assignment last-duplicate-wins; verified absmax=0.0 rounds 1-5).
__global__ void ppscatter_vote(const int* __restrict__ coords, int n,
                               int* __restrict__ winner) {
    int v = blockIdx.x * blockDim.x + threadIdx.x;
    if (v >= n) return;
    int b = coords[3 * v + 0];
    int x = coords[3 * v + 1];
    int y = coords[3 * v + 2];
    atomicMax(&winner[b * NPIX + x * NYD + y], v);
}

// Gather v3: channel-grouped blocks for L1 reuse of feat/winner lines.
//   grid  = (pq_total/64, C/16), block = 1024 threads = 16 waves.
//   pq    = pixel-quad index: b[16:17] | x[7:15] | y4[0:6]  (262,144 total)
//   wave w (0..15) handles channel c = blockIdx.y*16 + w over the block's
//   64-quad span. All 16 waves load the SAME 64 winner int4s (1 KB) and the
//   SAME feat 64B lines (c*4 in [cg*64, cg*64+64) => one line per voxel per
//   block) -> L1-served after the first wave. Per-wave store: 64 lanes x 16B
//   contiguous at one c (the R3-mandated pattern); consecutive blockIdx.x
//   advance pq so each channel stream is linear. NON-TEMPORAL stores keep
//   the 268 MB write stream from evicting winner/feat from L1/L2.
__global__ void __launch_bounds__(1024, 2)
ppscatter_gather(const float* __restrict__ feat,
                 const int* __restrict__ winner,
                 nfloat4* __restrict__ out4) {
    int w = threadIdx.x >> 6;                 // 0..15: channel within group
    int l = threadIdx.x & 63;                 // 0..63: quad within span
    int pq = (blockIdx.x << 6) | l;           // pixel-quad index
    int c  = (blockIdx.y << 4) | w;           // channel 0..63

    const int4* win4 = (const int4*)winner;
    int4 wq = win4[pq];                       // winner[b][x][4*y4 ..]

    nfloat4 val = {0.f, 0.f, 0.f, 0.f};
    // Empty fast path: entries are -1 or >=0; AND == -1 iff all empty (~74%).
    if ((wq.x & wq.y & wq.z & wq.w) != -1) {
        if (wq.x >= 0) val.x = feat[(wq.x << 6) + c];
        if (wq.y >= 0) val.y = feat[(wq.y << 6) + c];
        if (wq.z >= 0) val.z = feat[(wq.z << 6) + c];
        if (wq.w >= 0) val.w = feat[(wq.w << 6) + c];
    }
    // out4 index: b[22:23] | c[16:21] | x[7:15] | y4[0:6]
    int o = ((pq >> 16) << 22) | (c << 16) | (pq & 0xFFFF);
    __builtin_nontemporal_store(val, &out4[o]);
}

extern "C" void kernel_launch(void* const* d_in, const int* in_sizes, int n_in,
                              void* d_out, int out_size, void* d_ws, size_t ws_size,
                              hipStream_t stream) {
    const float* feat  = (const float*)d_in[0];
    const int* coords  = (const int*)d_in[1];

    int n = in_sizes[1] / 3;            // 80000 voxels
    int* winner = (int*)d_ws;           // B*NX*NY ints = 4 MiB scratch

    const int T = 256;
    int B = out_size / (CD * NPIX);     // 4

    int n_win4 = (B * NPIX) / 4;        // 262144
    ppscatter_init_winner<<<(n_win4 + T - 1) / T, T, 0, stream>>>((int4*)winner, n_win4);

    ppscatter_vote<<<(n + T - 1) / T, T, 0, stream>>>(coords, n, winner);

    int pq_total = (B * NPIX) / 4;      // 262144 pixel-quads
    dim3 grid(pq_total / 64, CD / 16);  // (4096, 4)
    ppscatter_gather<<<grid, 1024, 0, stream>>>(feat, winner, (nfloat4*)d_out);
}